// Round 10
// baseline (756.833 us; speedup 1.0000x reference)
//
#include <hip/hip_runtime.h>
#include <math.h>

#define B_    2
#define S_    2048
#define HID_  1024
#define H_    16
#define D_    64
#define KEEP_ 204
#define QT_   16
#define QRS_  72    // ushorts per Q row in LDS (16B-aligned rows; b128 reads at floor)
#define SCS_  516   // sc row stride (floats): 512+4 -> score writes 2-way not 4-way
#define WQS_  34    // w16 q-row stride (ushorts): weight writes spread all 32 banks
#define WTS_  (16 * WQS_)   // 544 ushorts per 16q x 32k weight tile

typedef __attribute__((ext_vector_type(8))) short short8;
typedef __attribute__((ext_vector_type(4))) float f32x4;

// order-preserving fp32 -> uint32 mapping (larger float <=> larger uint)
__device__ __forceinline__ unsigned f2u_ord(float x) {
    unsigned b = __float_as_uint(x);
    return (b & 0x80000000u) ? ~b : (b | 0x80000000u);
}
__device__ __forceinline__ float u2f_ord(unsigned u) {
    unsigned b = (u & 0x80000000u) ? (u ^ 0x80000000u) : ~u;
    return __uint_as_float(b);
}
__device__ __forceinline__ float wave_sum(float x) {
    #pragma unroll
    for (int off = 32; off > 0; off >>= 1) x += __shfl_xor(x, off);
    return x;
}
__device__ __forceinline__ unsigned wave_max_u(unsigned x) {
    #pragma unroll
    for (int off = 32; off > 0; off >>= 1) {
        unsigned t = __shfl_xor(x, off);
        x = (t > x) ? t : x;
    }
    return x;
}
__device__ __forceinline__ unsigned short bf16rn(float x) {
    unsigned u = __float_as_uint(x);
    return (unsigned short)((u + 0x7fffu + ((u >> 16) & 1u)) >> 16);
}
__device__ __forceinline__ float bfhi2f(unsigned short h) {
    return __uint_as_float((unsigned)h << 16);
}
// async global->LDS, 16B per lane; LDS dest = wave-uniform base + lane*16
__device__ __forceinline__ void gld_lds16(const unsigned short* g, unsigned short* l) {
    __builtin_amdgcn_global_load_lds(
        (const __attribute__((address_space(1))) void*)g,
        (__attribute__((address_space(3))) void*)l,
        16, 0, 0);
}

// ---------------- x (flat fp32) -> bf16 hi/lo ----------------
__global__ __launch_bounds__(256) void conv_x_k(
    const float* __restrict__ X,
    unsigned short* __restrict__ Xh, unsigned short* __restrict__ Xl)
{
    const int i = blockIdx.x * 256 + threadIdx.x;
    const float4 v = ((const float4*)X)[i];
    ushort4 h, l;
    h.x = bf16rn(v.x); l.x = bf16rn(v.x - bfhi2f(h.x));
    h.y = bf16rn(v.y); l.y = bf16rn(v.y - bfhi2f(h.y));
    h.z = bf16rn(v.z); l.z = bf16rn(v.z - bfhi2f(h.z));
    h.w = bf16rn(v.w); l.w = bf16rn(v.w - bfhi2f(h.w));
    ((ushort4*)Xh)[i] = h;
    ((ushort4*)Xl)[i] = l;
}

// ---------------- W [K][N] fp32 -> Wt [N][K] bf16 hi/lo (transpose) ----------------
__global__ __launch_bounds__(256) void conv_wT_k(
    const float* __restrict__ W,
    unsigned short* __restrict__ Wth, unsigned short* __restrict__ Wtl)
{
    __shared__ float t[64][65];
    const int k0 = blockIdx.y * 64, n0 = blockIdx.x * 64;
    const int r = threadIdx.x >> 4, c4 = (threadIdx.x & 15) * 4;
    #pragma unroll
    for (int i = 0; i < 4; i++) {
        const float4 v = *(const float4*)&W[(size_t)(k0 + r + 16 * i) * HID_ + n0 + c4];
        t[r + 16 * i][c4 + 0] = v.x;
        t[r + 16 * i][c4 + 1] = v.y;
        t[r + 16 * i][c4 + 2] = v.z;
        t[r + 16 * i][c4 + 3] = v.w;
    }
    __syncthreads();
    #pragma unroll
    for (int i = 0; i < 4; i++) {
        const int n = r + 16 * i;
        float a0 = t[c4 + 0][n], a1 = t[c4 + 1][n], a2 = t[c4 + 2][n], a3 = t[c4 + 3][n];
        ushort4 h, l;
        h.x = bf16rn(a0); l.x = bf16rn(a0 - bfhi2f(h.x));
        h.y = bf16rn(a1); l.y = bf16rn(a1 - bfhi2f(h.y));
        h.z = bf16rn(a2); l.z = bf16rn(a2 - bfhi2f(h.z));
        h.w = bf16rn(a3); l.w = bf16rn(a3 - bfhi2f(h.w));
        const size_t idx = (size_t)(n0 + n) * HID_ + k0 + c4;
        *(ushort4*)&Wth[idx] = h;
        *(ushort4*)&Wtl[idx] = l;
    }
}

// ---------------- fused Q/K/V split-bf16 MFMA GEMM (128x128 LDS-staged) ----------------
// (unchanged from round 9: m97-structure, global_load_lds width 16, 4 waves,
//  64x64 quadrant per wave, 3-term split-bf16, bit-identical accumulation order)
__global__ __launch_bounds__(256) void gemm_qkv_k(
    const unsigned short* __restrict__ Ah, const unsigned short* __restrict__ Al,
    const unsigned short* __restrict__ Bhq, const unsigned short* __restrict__ Blq,
    const unsigned short* __restrict__ Bhk, const unsigned short* __restrict__ Blk,
    const unsigned short* __restrict__ Bhv, const unsigned short* __restrict__ Blv,
    const float* __restrict__ bq, const float* __restrict__ bk, const float* __restrict__ bv,
    unsigned short* __restrict__ Qh, unsigned short* __restrict__ Ql,
    unsigned short* __restrict__ Kh, unsigned short* __restrict__ Kl,
    unsigned short* __restrict__ Vt)
{
    const int z = blockIdx.z;
    const unsigned short* Bth = (z == 0) ? Bhq : (z == 1) ? Bhk : Bhv;
    const unsigned short* Btl = (z == 0) ? Blq : (z == 1) ? Blk : Blv;
    const float* bias = (z == 0) ? bq : (z == 1) ? bk : bv;

    const int tid = threadIdx.x;
    const int lane = tid & 63;
    const int w = tid >> 6;              // wave 0..3
    const int wr = w >> 1, wc = w & 1;   // 2x2 wave grid over the 128x128 tile
    const int m0 = blockIdx.y * 128;
    const int n0 = blockIdx.x * 128;
    const int mrow = lane & 15, quad = lane >> 4;

    __shared__ __align__(16) unsigned short lds[16384];   // 4 x [128][32] tiles (32 KB)
    unsigned short* ldsAh = lds;
    unsigned short* ldsAl = lds + 4096;
    unsigned short* ldsBh = lds + 8192;
    unsigned short* ldsBl = lds + 12288;

    f32x4 acc[4][4];
    #pragma unroll
    for (int mt = 0; mt < 4; mt++)
        #pragma unroll
        for (int nt = 0; nt < 4; nt++)
            acc[mt][nt] = (f32x4){0.f, 0.f, 0.f, 0.f};

    const int srow = w * 32 + (lane >> 2);
    const int scol = (lane & 3) * 8;
    const size_t aoff = (size_t)(m0 + srow) * HID_ + scol;
    const size_t boff = (size_t)(n0 + srow) * HID_ + scol;
    unsigned short* dst0 = lds + (w * 32) * 32;          // lane*16B auto-offset
    unsigned short* dst1 = lds + (w * 32 + 16) * 32;

    #pragma unroll 1
    for (int k0 = 0; k0 < HID_; k0 += 32) {
        gld_lds16(Ah  + aoff + k0,             dst0);
        gld_lds16(Ah  + aoff + k0 + 16 * HID_, dst1);
        gld_lds16(Al  + aoff + k0,             dst0 + 4096);
        gld_lds16(Al  + aoff + k0 + 16 * HID_, dst1 + 4096);
        gld_lds16(Bth + boff + k0,             dst0 + 8192);
        gld_lds16(Bth + boff + k0 + 16 * HID_, dst1 + 8192);
        gld_lds16(Btl + boff + k0,             dst0 + 12288);
        gld_lds16(Btl + boff + k0 + 16 * HID_, dst1 + 12288);
        __syncthreads();   // drains vmcnt; tiles ready

        short8 bh[4], bl[4];
        #pragma unroll
        for (int nt = 0; nt < 4; nt++) {
            const int br = (wc * 64 + nt * 16 + mrow) * 32 + quad * 8;
            bh[nt] = *(const short8*)&ldsBh[br];
            bl[nt] = *(const short8*)&ldsBl[br];
        }
        #pragma unroll
        for (int mt = 0; mt < 4; mt++) {
            const int ar = (wr * 64 + mt * 16 + mrow) * 32 + quad * 8;
            const short8 ah = *(const short8*)&ldsAh[ar];
            const short8 al = *(const short8*)&ldsAl[ar];
            #pragma unroll
            for (int nt = 0; nt < 4; nt++) {
                acc[mt][nt] = __builtin_amdgcn_mfma_f32_16x16x32_bf16(al, bh[nt], acc[mt][nt], 0, 0, 0);
                acc[mt][nt] = __builtin_amdgcn_mfma_f32_16x16x32_bf16(ah, bl[nt], acc[mt][nt], 0, 0, 0);
                acc[mt][nt] = __builtin_amdgcn_mfma_f32_16x16x32_bf16(ah, bh[nt], acc[mt][nt], 0, 0, 0);
            }
        }
        __syncthreads();   // reads done; next stage may overwrite
    }

    const float scale = (z == 0) ? 0.125f : 1.0f;
    #pragma unroll
    for (int nt = 0; nt < 4; nt++) {
        const int cn = n0 + wc * 64 + nt * 16 + mrow;
        const float bs = bias[cn];
        const int h = cn >> 6, d = cn & 63;
        #pragma unroll
        for (int mt = 0; mt < 4; mt++) {
            #pragma unroll
            for (int reg = 0; reg < 4; reg++) {
                const int rm = m0 + wr * 64 + mt * 16 + quad * 4 + reg;
                const int b = rm >> 11, s = rm & (S_ - 1);
                const float v = acc[mt][nt][reg] + bs;
                if (z == 2) {
                    // transposed: Vt[bh][d][s]
                    Vt[((size_t)(b * H_ + h) * D_ + d) * S_ + s] = bf16rn(v);
                } else {
                    const size_t idx = ((size_t)(b * H_ + h) * S_ + s) * D_ + d;
                    const float vs = v * scale;
                    const unsigned short hb = bf16rn(vs);
                    const unsigned short lb = bf16rn(vs - bfhi2f(hb));
                    if (z == 0) { Qh[idx] = hb; Ql[idx] = lb; }
                    else        { Kh[idx] = hb; Kl[idx] = lb; }
                }
            }
        }
    }
}

// ---------------- O-GEMM: out = AO @ Wo + bo (fp32 out), 128x128 LDS-staged --------
__global__ __launch_bounds__(256) void gemm_o_k(
    const unsigned short* __restrict__ Ah, const unsigned short* __restrict__ Al,
    const unsigned short* __restrict__ Bth, const unsigned short* __restrict__ Btl,
    const float* __restrict__ bias, float* __restrict__ Y)
{
    const int tid = threadIdx.x;
    const int lane = tid & 63;
    const int w = tid >> 6;
    const int wr = w >> 1, wc = w & 1;
    const int m0 = blockIdx.y * 128;
    const int n0 = blockIdx.x * 128;
    const int mrow = lane & 15, quad = lane >> 4;

    __shared__ __align__(16) unsigned short lds[16384];
    unsigned short* ldsAh = lds;
    unsigned short* ldsAl = lds + 4096;
    unsigned short* ldsBh = lds + 8192;
    unsigned short* ldsBl = lds + 12288;

    f32x4 acc[4][4];
    #pragma unroll
    for (int mt = 0; mt < 4; mt++)
        #pragma unroll
        for (int nt = 0; nt < 4; nt++)
            acc[mt][nt] = (f32x4){0.f, 0.f, 0.f, 0.f};

    const int srow = w * 32 + (lane >> 2);
    const int scol = (lane & 3) * 8;
    const size_t aoff = (size_t)(m0 + srow) * HID_ + scol;
    const size_t boff = (size_t)(n0 + srow) * HID_ + scol;
    unsigned short* dst0 = lds + (w * 32) * 32;
    unsigned short* dst1 = lds + (w * 32 + 16) * 32;

    #pragma unroll 1
    for (int k0 = 0; k0 < HID_; k0 += 32) {
        gld_lds16(Ah  + aoff + k0,             dst0);
        gld_lds16(Ah  + aoff + k0 + 16 * HID_, dst1);
        gld_lds16(Al  + aoff + k0,             dst0 + 4096);
        gld_lds16(Al  + aoff + k0 + 16 * HID_, dst1 + 4096);
        gld_lds16(Bth + boff + k0,             dst0 + 8192);
        gld_lds16(Bth + boff + k0 + 16 * HID_, dst1 + 8192);
        gld_lds16(Btl + boff + k0,             dst0 + 12288);
        gld_lds16(Btl + boff + k0 + 16 * HID_, dst1 + 12288);
        __syncthreads();

        short8 bh[4], bl[4];
        #pragma unroll
        for (int nt = 0; nt < 4; nt++) {
            const int br = (wc * 64 + nt * 16 + mrow) * 32 + quad * 8;
            bh[nt] = *(const short8*)&ldsBh[br];
            bl[nt] = *(const short8*)&ldsBl[br];
        }
        #pragma unroll
        for (int mt = 0; mt < 4; mt++) {
            const int ar = (wr * 64 + mt * 16 + mrow) * 32 + quad * 8;
            const short8 ah = *(const short8*)&ldsAh[ar];
            const short8 al = *(const short8*)&ldsAl[ar];
            #pragma unroll
            for (int nt = 0; nt < 4; nt++) {
                acc[mt][nt] = __builtin_amdgcn_mfma_f32_16x16x32_bf16(al, bh[nt], acc[mt][nt], 0, 0, 0);
                acc[mt][nt] = __builtin_amdgcn_mfma_f32_16x16x32_bf16(ah, bl[nt], acc[mt][nt], 0, 0, 0);
                acc[mt][nt] = __builtin_amdgcn_mfma_f32_16x16x32_bf16(ah, bh[nt], acc[mt][nt], 0, 0, 0);
            }
        }
        __syncthreads();
    }

    #pragma unroll
    for (int nt = 0; nt < 4; nt++) {
        const int cn = n0 + wc * 64 + nt * 16 + mrow;
        const float bs = bias[cn];
        #pragma unroll
        for (int mt = 0; mt < 4; mt++)
            #pragma unroll
            for (int reg = 0; reg < 4; reg++) {
                const int rm = m0 + wr * 64 + mt * 16 + quad * 4 + reg;
                Y[(size_t)rm * HID_ + cn] = acc[mt][nt][reg] + bs;
            }
    }
}

// ---------------- fused MFMA scores + exact top-204 + DENSE-MFMA sparse-softmax PV ----
// ROUND-10: de-lockstep + conflict pads (no register-pressure change):
//  (a) sc double-buffered [2][16][SCS_] -> ONE barrier per score round (was 2);
//      round r+1 writes buf (r+1)&1 while extraction of round r proceeds.
//      Barriers/block: 11 -> 8.
//  (b) sc col stride 516: score b32 writes gain the quad term in the bank index
//      -> 2-way (free) instead of 4-way.
//  (c) w16 q-row stride 34 (tile 544 ushorts): weight b16 writes spread across
//      all 32 banks (lanes 32-63 no longer alias lanes 0-31).
// Same arithmetic, same order -> absmax must stay 0.001464844.
__global__ __launch_bounds__(1024, 8) void attn_topk_k(
    const unsigned short* __restrict__ Qhi, const unsigned short* __restrict__ Qlo,
    const unsigned short* __restrict__ Khi, const unsigned short* __restrict__ Klo,
    const unsigned short* __restrict__ Vt,
    unsigned short* __restrict__ AOh, unsigned short* __restrict__ AOl)
{
    const int tid = threadIdx.x;
    const int wv = tid >> 6;                  // 0..15 — this wave's query row
    const int lane = tid & 63;
    // XCD-locality remap: 4 bh per XCD -> K+Vt working set < one L2
    const int xcd = blockIdx.x & 7;
    const int w = blockIdx.x >> 3;
    const int bh = xcd * 4 + (w >> 7);
    const int q0 = (w & 127) * QT_;
    const int b = bh >> 4, h = bh & (H_ - 1);

    // region 0..69632: union of sc[2][16][SCS_] (66048 B) and w16 64xWTS_ (69632 B)
    __shared__ __align__(16) unsigned char smem[69632 + 4096 + 64 + 2 * 16 * QRS_ * 2];
    unsigned short* w16 = (unsigned short*)smem;
    float* partial = (float*)(smem + 69632);                 // [16][64]
    float* denomL  = (float*)(smem + 69632 + 4096);          // [16]
    unsigned short* qh_l = (unsigned short*)(smem + 69632 + 4096 + 64);  // [16][QRS_]
    unsigned short* ql_l = qh_l + 16 * QRS_;

    const int mrow = lane & 15, quad = lane >> 4;

    // ---- stage Q (16 rows x 64 d, hi+lo) into LDS: 1 ushort/plane/thread ----
    {
        const int row = tid >> 6, d = tid & 63;
        const size_t g = ((size_t)bh * S_ + q0 + row) * D_ + d;
        qh_l[row * QRS_ + d] = Qhi[g];
        ql_l[row * QRS_ + d] = Qlo[g];
    }
    __syncthreads();

    const unsigned short* Kh_b = Khi + (size_t)bh * S_ * D_;   // SGPR base
    const unsigned short* Kl_b = Klo + (size_t)bh * S_ * D_;
    unsigned uu[32];   // slot (r*8+c) <-> key j = r*512 + c*64 + lane

    const int qoff = mrow * QRS_;

    #pragma unroll
    for (int r = 0; r < 4; r++) {
        float* scb = (float*)smem + (r & 1) * (16 * SCS_);   // this round's buffer
        int koff = (r * 512 + wv * 32 + mrow) * D_ + quad * 8;   // 32-bit voffset
        #pragma unroll 1
        for (int tl = 0; tl < 2; tl++) {
            f32x4 acc = {0.f, 0.f, 0.f, 0.f};
            {   // k = 0..31: Q half 0 from LDS, B half 0 from global
                const short8 Ah0 = *(const short8*)&qh_l[qoff + quad * 8];
                const short8 Al0 = *(const short8*)&ql_l[qoff + quad * 8];
                const short8 Bh0 = *(const short8*)&Kh_b[koff];
                const short8 Bl0 = *(const short8*)&Kl_b[koff];
                __builtin_amdgcn_s_setprio(1);
                acc = __builtin_amdgcn_mfma_f32_16x16x32_bf16(Al0, Bl0, acc, 0, 0, 0);
                acc = __builtin_amdgcn_mfma_f32_16x16x32_bf16(Al0, Bh0, acc, 0, 0, 0);
                acc = __builtin_amdgcn_mfma_f32_16x16x32_bf16(Ah0, Bl0, acc, 0, 0, 0);
                acc = __builtin_amdgcn_mfma_f32_16x16x32_bf16(Ah0, Bh0, acc, 0, 0, 0);
                __builtin_amdgcn_s_setprio(0);
            }
            {   // k = 32..63: Q half 1, B half 1 (same registers recycled)
                const short8 Ah1 = *(const short8*)&qh_l[qoff + 32 + quad * 8];
                const short8 Al1 = *(const short8*)&ql_l[qoff + 32 + quad * 8];
                const short8 Bh1 = *(const short8*)&Kh_b[koff + 32];
                const short8 Bl1 = *(const short8*)&Kl_b[koff + 32];
                __builtin_amdgcn_s_setprio(1);
                acc = __builtin_amdgcn_mfma_f32_16x16x32_bf16(Al1, Bl1, acc, 0, 0, 0);
                acc = __builtin_amdgcn_mfma_f32_16x16x32_bf16(Al1, Bh1, acc, 0, 0, 0);
                acc = __builtin_amdgcn_mfma_f32_16x16x32_bf16(Ah1, Bl1, acc, 0, 0, 0);
                acc = __builtin_amdgcn_mfma_f32_16x16x32_bf16(Ah1, Bh1, acc, 0, 0, 0);
                __builtin_amdgcn_s_setprio(0);
            }
            // C: row = quad*4+reg (0..15 = query), col = lane&15 (key in tile)
            const int colb = wv * 32 + tl * 16 + mrow;
            #pragma unroll
            for (int reg = 0; reg < 4; reg++)
                scb[(quad * 4 + reg) * SCS_ + colb] = acc[reg];
            koff += 16 * D_;
        }
        __syncthreads();   // round-r strips visible; next round writes other buffer
        #pragma unroll
        for (int c = 0; c < 8; c++)
            uu[r * 8 + c] = f2u_ord(scb[wv * SCS_ + c * 64 + lane]);
        // no trailing barrier: round r+2 (same buffer) is fenced by barrier r+1
    }
    __syncthreads();   // all extractions done before weight writes reuse the region

    // row max (ordered uints); sparse row includes zeros -> clamp to 0
    unsigned um = 0u;
    #pragma unroll
    for (int c = 0; c < 32; c++) { const unsigned t = uu[c]; um = (t > um) ? t : um; }
    um = wave_max_u(um);
    um = __builtin_amdgcn_readfirstlane(um);   // keep threshold chain scalar
    const float m = fmaxf(u2f_ord(um), 0.0f);
    const float em = __expf(-m);

    // ---- exact threshold: ballot-counted radix-2 bit-descent ----
    unsigned p = 0;
    int cge = S_;          // count of values >= p (p=0 -> all)
    #pragma unroll 1
    for (int bit = 31; bit >= 0; bit--) {
        if (cge == KEEP_) break;
        const unsigned trial = p | (1u << bit);
        if (trial > um) continue;
        int c = 0;
        #pragma unroll
        for (int i = 0; i < 32; i++)
            c += (int)__popcll(__ballot(uu[i] >= trial));
        if (c >= KEEP_) { p = trial; cge = c; }
    }
    const unsigned T = p;

    // ---- tie selection ----
    unsigned tieMask = 0;
    if (cge == KEEP_) {
        // exact hit: all ties at T are selected
        #pragma unroll
        for (int c = 0; c < 32; c++)
            if (uu[c] == T) tieMask |= 1u << c;
    } else {
        // rare path: take first `rem' ties in ascending j
        int cgt = 0;
        #pragma unroll
        for (int i = 0; i < 32; i++)
            cgt += (int)__popcll(__ballot(uu[i] > T));
        int need = KEEP_ - cgt;                // #ties to take (>=1)
        const unsigned long long below = (1ULL << lane) - 1ULL;
        #pragma unroll
        for (int c = 0; c < 32; c++) {
            const bool eq = (uu[c] == T);
            const unsigned long long mg = __ballot(eq);
            if (eq && (int)__popcll(mg & below) < need) tieMask |= 1u << c;
            const int cnt = (int)__popcll(mg);
            need -= (cnt < need) ? cnt : need;
        }
    }

    // ---- dense bf16 weight row + denominator from stored weights ----
    // slot i = r*8+c2 -> key j = r*512 + c2*64 + lane -> tile ch = j>>5 =
    // r*16 + c2*2 + (lane>>5), kk = lane&31; layout w16[ch*WTS_ + q*WQS_ + kk]
    float esum = 0.f;
    {
        const int lh = lane >> 5;
        const int kk = lane & 31;
        #pragma unroll
        for (int i = 0; i < 32; i++) {
            const unsigned u = uu[i];
            const bool sel = (u > T) || ((tieMask >> i) & 1u);
            const float wgt = sel ? __expf(u2f_ord(u) - m) : em;
            const unsigned short wb = bf16rn(wgt);
            esum += bfhi2f(wb);
            const int ch = (i >> 3) * 16 + (i & 7) * 2 + lh;
            w16[ch * WTS_ + wv * WQS_ + kk] = wb;
        }
    }
    const float denom = wave_sum(esum);
    if (lane == 0) denomL[wv] = denom;
    partial[tid] = 0.f;    // zero PV accumulator (exactly 1024 floats)
    __syncthreads();       // weights + denoms + zeroed partial visible

    // ---- PV via MFMA: wave = (ntile = wv&3 -> d-cols, kq = wv>>2 -> key quarter)
    {
        const int ntile = wv & 3;
        const int kq = wv >> 2;
        const unsigned short* VtB =
            Vt + ((size_t)bh * D_ + ntile * 16 + mrow) * S_ + kq * 512 + quad * 8;
        const unsigned short* wbase = w16 + kq * 16 * WTS_ + mrow * WQS_ + quad * 8;
        f32x4 pacc0 = {0.f, 0.f, 0.f, 0.f};
        f32x4 pacc1 = {0.f, 0.f, 0.f, 0.f};
        #pragma unroll 2
        for (int ch = 0; ch < 16; ch += 2) {
            const short8 aw0 = *(const short8*)&wbase[ch * WTS_];
            const short8 bv0 = *(const short8*)&VtB[ch * 32];
            const short8 aw1 = *(const short8*)&wbase[(ch + 1) * WTS_];
            const short8 bv1 = *(const short8*)&VtB[(ch + 1) * 32];
            pacc0 = __builtin_amdgcn_mfma_f32_16x16x32_bf16(aw0, bv0, pacc0, 0, 0, 0);
            pacc1 = __builtin_amdgcn_mfma_f32_16x16x32_bf16(aw1, bv1, pacc1, 0, 0, 0);
        }
        const f32x4 pacc = pacc0 + pacc1;
        // C: row = quad*4+reg (query), col = lane&15 (d within ntile)
        #pragma unroll
        for (int reg = 0; reg < 4; reg++)
            atomicAdd(&partial[(quad * 4 + reg) * 64 + ntile * 16 + mrow], pacc[reg]);
    }
    __syncthreads();   // partials reduced

    // ---- normalize, write AO (bf16 hi/lo) ----
    {
        const int q = tid >> 6;       // 0..15
        const int d = tid & 63;
        const float o = partial[q * 64 + d] / denomL[q];
        const unsigned short hb = bf16rn(o);
        const unsigned short lb = bf16rn(o - bfhi2f(hb));
        const size_t oidx = ((size_t)(b * S_ + q0 + q)) * HID_ + h * D_ + d;
        AOh[oidx] = hb;
        AOl[oidx] = lb;
    }
}

extern "C" void kernel_launch(void* const* d_in, const int* in_sizes, int n_in,
                              void* d_out, int out_size, void* d_ws, size_t ws_size,
                              hipStream_t stream) {
    const float* x  = (const float*)d_in[0];
    const float* Wq = (const float*)d_in[1];
    const float* bq = (const float*)d_in[2];
    const float* Wk = (const float*)d_in[3];
    const float* bk = (const float*)d_in[4];
    const float* Wv = (const float*)d_in[5];
    const float* bv = (const float*)d_in[6];
    const float* Wo = (const float*)d_in[7];
    const float* bo = (const float*)d_in[8];
    float* out = (float*)d_out;

    const size_t NQ = (size_t)B_ * H_ * S_ * D_;   // 4,194,304 elements
    const size_t NW = (size_t)HID_ * HID_;         // 1,048,576 elements
    unsigned short* p = (unsigned short*)d_ws;
    unsigned short* xh   = p; p += NQ;   // also AOh (x dead after QKV GEMM)
    unsigned short* xl   = p; p += NQ;   // also AOl
    unsigned short* Wt_h[4];
    unsigned short* Wt_l[4];
    for (int i = 0; i < 4; i++) { Wt_h[i] = p; p += NW; Wt_l[i] = p; p += NW; }
    unsigned short* Qhi = p; p += NQ;
    unsigned short* Qlo = p; p += NQ;
    unsigned short* Khi = p; p += NQ;
    unsigned short* Klo = p; p += NQ;
    unsigned short* Vt  = p; p += NQ;
    unsigned short* AOh = xh;
    unsigned short* AOl = xl;

    dim3 blk(256);
    conv_x_k<<<dim3(NQ / 1024), blk, 0, stream>>>(x, xh, xl);
    conv_wT_k<<<dim3(16, 16), blk, 0, stream>>>(Wq, Wt_h[0], Wt_l[0]);
    conv_wT_k<<<dim3(16, 16), blk, 0, stream>>>(Wk, Wt_h[1], Wt_l[1]);
    conv_wT_k<<<dim3(16, 16), blk, 0, stream>>>(Wv, Wt_h[2], Wt_l[2]);
    conv_wT_k<<<dim3(16, 16), blk, 0, stream>>>(Wo, Wt_h[3], Wt_l[3]);

    dim3 gqkv(HID_ / 128, (B_ * S_) / 128, 3);
    gemm_qkv_k<<<gqkv, blk, 0, stream>>>(xh, xl,
        Wt_h[0], Wt_l[0], Wt_h[1], Wt_l[1], Wt_h[2], Wt_l[2],
        bq, bk, bv, Qhi, Qlo, Khi, Klo, Vt);
    attn_topk_k<<<dim3(B_ * H_ * (S_ / QT_)), dim3(1024), 0, stream>>>(
        Qhi, Qlo, Khi, Klo, Vt, AOh, AOl);
    dim3 go(HID_ / 128, (B_ * S_) / 128);
    gemm_o_k<<<go, blk, 0, stream>>>(AOh, AOl, Wt_h[3], Wt_l[3], bo, out);
}

// Round 12
// 741.659 us; speedup vs baseline: 1.0205x; 1.0205x over previous
//
#include <hip/hip_runtime.h>
#include <math.h>

#define B_    2
#define S_    2048
#define HID_  1024
#define H_    16
#define D_    64
#define KEEP_ 204
#define QT_   16
#define QRS_  72   // ushorts per Q row in LDS (16B-aligned rows; b128 reads at floor)

typedef __attribute__((ext_vector_type(8))) short short8;
typedef __attribute__((ext_vector_type(4))) float f32x4;

// order-preserving fp32 -> uint32 mapping (larger float <=> larger uint)
__device__ __forceinline__ unsigned f2u_ord(float x) {
    unsigned b = __float_as_uint(x);
    return (b & 0x80000000u) ? ~b : (b | 0x80000000u);
}
__device__ __forceinline__ float u2f_ord(unsigned u) {
    unsigned b = (u & 0x80000000u) ? (u ^ 0x80000000u) : ~u;
    return __uint_as_float(b);
}
__device__ __forceinline__ float wave_sum(float x) {
    #pragma unroll
    for (int off = 32; off > 0; off >>= 1) x += __shfl_xor(x, off);
    return x;
}
__device__ __forceinline__ unsigned wave_max_u(unsigned x) {
    #pragma unroll
    for (int off = 32; off > 0; off >>= 1) {
        unsigned t = __shfl_xor(x, off);
        x = (t > x) ? t : x;
    }
    return x;
}
__device__ __forceinline__ unsigned short bf16rn(float x) {
    unsigned u = __float_as_uint(x);
    return (unsigned short)((u + 0x7fffu + ((u >> 16) & 1u)) >> 16);
}
__device__ __forceinline__ float bfhi2f(unsigned short h) {
    return __uint_as_float((unsigned)h << 16);
}
// async global->LDS, 16B per lane; LDS dest = wave-uniform base + lane*16
__device__ __forceinline__ void gld_lds16(const unsigned short* g, unsigned short* l) {
    __builtin_amdgcn_global_load_lds(
        (const __attribute__((address_space(1))) void*)g,
        (__attribute__((address_space(3))) void*)l,
        16, 0, 0);
}

// ---------------- x (flat fp32) -> bf16 hi/lo ----------------
__global__ __launch_bounds__(256) void conv_x_k(
    const float* __restrict__ X,
    unsigned short* __restrict__ Xh, unsigned short* __restrict__ Xl)
{
    const int i = blockIdx.x * 256 + threadIdx.x;
    const float4 v = ((const float4*)X)[i];
    ushort4 h, l;
    h.x = bf16rn(v.x); l.x = bf16rn(v.x - bfhi2f(h.x));
    h.y = bf16rn(v.y); l.y = bf16rn(v.y - bfhi2f(h.y));
    h.z = bf16rn(v.z); l.z = bf16rn(v.z - bfhi2f(h.z));
    h.w = bf16rn(v.w); l.w = bf16rn(v.w - bfhi2f(h.w));
    ((ushort4*)Xh)[i] = h;
    ((ushort4*)Xl)[i] = l;
}

// ---------------- W [K][N] fp32 -> Wt [N][K] bf16 hi/lo (transpose) ----------------
__global__ __launch_bounds__(256) void conv_wT_k(
    const float* __restrict__ W,
    unsigned short* __restrict__ Wth, unsigned short* __restrict__ Wtl)
{
    __shared__ float t[64][65];
    const int k0 = blockIdx.y * 64, n0 = blockIdx.x * 64;
    const int r = threadIdx.x >> 4, c4 = (threadIdx.x & 15) * 4;
    #pragma unroll
    for (int i = 0; i < 4; i++) {
        const float4 v = *(const float4*)&W[(size_t)(k0 + r + 16 * i) * HID_ + n0 + c4];
        t[r + 16 * i][c4 + 0] = v.x;
        t[r + 16 * i][c4 + 1] = v.y;
        t[r + 16 * i][c4 + 2] = v.z;
        t[r + 16 * i][c4 + 3] = v.w;
    }
    __syncthreads();
    #pragma unroll
    for (int i = 0; i < 4; i++) {
        const int n = r + 16 * i;
        float a0 = t[c4 + 0][n], a1 = t[c4 + 1][n], a2 = t[c4 + 2][n], a3 = t[c4 + 3][n];
        ushort4 h, l;
        h.x = bf16rn(a0); l.x = bf16rn(a0 - bfhi2f(h.x));
        h.y = bf16rn(a1); l.y = bf16rn(a1 - bfhi2f(h.y));
        h.z = bf16rn(a2); l.z = bf16rn(a2 - bfhi2f(h.z));
        h.w = bf16rn(a3); l.w = bf16rn(a3 - bfhi2f(h.w));
        const size_t idx = (size_t)(n0 + n) * HID_ + k0 + c4;
        *(ushort4*)&Wth[idx] = h;
        *(ushort4*)&Wtl[idx] = l;
    }
}

// ---------------- fused Q/K/V split-bf16 MFMA GEMM (128x128 LDS-staged) ----------------
// (unchanged from round 9: m97-structure, global_load_lds width 16, 4 waves,
//  64x64 quadrant per wave, 3-term split-bf16, bit-identical accumulation order)
__global__ __launch_bounds__(256) void gemm_qkv_k(
    const unsigned short* __restrict__ Ah, const unsigned short* __restrict__ Al,
    const unsigned short* __restrict__ Bhq, const unsigned short* __restrict__ Blq,
    const unsigned short* __restrict__ Bhk, const unsigned short* __restrict__ Blk,
    const unsigned short* __restrict__ Bhv, const unsigned short* __restrict__ Blv,
    const float* __restrict__ bq, const float* __restrict__ bk, const float* __restrict__ bv,
    unsigned short* __restrict__ Qh, unsigned short* __restrict__ Ql,
    unsigned short* __restrict__ Kh, unsigned short* __restrict__ Kl,
    unsigned short* __restrict__ Vt)
{
    const int z = blockIdx.z;
    const unsigned short* Bth = (z == 0) ? Bhq : (z == 1) ? Bhk : Bhv;
    const unsigned short* Btl = (z == 0) ? Blq : (z == 1) ? Blk : Blv;
    const float* bias = (z == 0) ? bq : (z == 1) ? bk : bv;

    const int tid = threadIdx.x;
    const int lane = tid & 63;
    const int w = tid >> 6;              // wave 0..3
    const int wr = w >> 1, wc = w & 1;   // 2x2 wave grid over the 128x128 tile
    const int m0 = blockIdx.y * 128;
    const int n0 = blockIdx.x * 128;
    const int mrow = lane & 15, quad = lane >> 4;

    __shared__ __align__(16) unsigned short lds[16384];   // 4 x [128][32] tiles (32 KB)
    unsigned short* ldsAh = lds;
    unsigned short* ldsAl = lds + 4096;
    unsigned short* ldsBh = lds + 8192;
    unsigned short* ldsBl = lds + 12288;

    f32x4 acc[4][4];
    #pragma unroll
    for (int mt = 0; mt < 4; mt++)
        #pragma unroll
        for (int nt = 0; nt < 4; nt++)
            acc[mt][nt] = (f32x4){0.f, 0.f, 0.f, 0.f};

    const int srow = w * 32 + (lane >> 2);
    const int scol = (lane & 3) * 8;
    const size_t aoff = (size_t)(m0 + srow) * HID_ + scol;
    const size_t boff = (size_t)(n0 + srow) * HID_ + scol;
    unsigned short* dst0 = lds + (w * 32) * 32;          // lane*16B auto-offset
    unsigned short* dst1 = lds + (w * 32 + 16) * 32;

    #pragma unroll 1
    for (int k0 = 0; k0 < HID_; k0 += 32) {
        gld_lds16(Ah  + aoff + k0,             dst0);
        gld_lds16(Ah  + aoff + k0 + 16 * HID_, dst1);
        gld_lds16(Al  + aoff + k0,             dst0 + 4096);
        gld_lds16(Al  + aoff + k0 + 16 * HID_, dst1 + 4096);
        gld_lds16(Bth + boff + k0,             dst0 + 8192);
        gld_lds16(Bth + boff + k0 + 16 * HID_, dst1 + 8192);
        gld_lds16(Btl + boff + k0,             dst0 + 12288);
        gld_lds16(Btl + boff + k0 + 16 * HID_, dst1 + 12288);
        __syncthreads();   // drains vmcnt; tiles ready

        short8 bh[4], bl[4];
        #pragma unroll
        for (int nt = 0; nt < 4; nt++) {
            const int br = (wc * 64 + nt * 16 + mrow) * 32 + quad * 8;
            bh[nt] = *(const short8*)&ldsBh[br];
            bl[nt] = *(const short8*)&ldsBl[br];
        }
        #pragma unroll
        for (int mt = 0; mt < 4; mt++) {
            const int ar = (wr * 64 + mt * 16 + mrow) * 32 + quad * 8;
            const short8 ah = *(const short8*)&ldsAh[ar];
            const short8 al = *(const short8*)&ldsAl[ar];
            #pragma unroll
            for (int nt = 0; nt < 4; nt++) {
                acc[mt][nt] = __builtin_amdgcn_mfma_f32_16x16x32_bf16(al, bh[nt], acc[mt][nt], 0, 0, 0);
                acc[mt][nt] = __builtin_amdgcn_mfma_f32_16x16x32_bf16(ah, bl[nt], acc[mt][nt], 0, 0, 0);
                acc[mt][nt] = __builtin_amdgcn_mfma_f32_16x16x32_bf16(ah, bh[nt], acc[mt][nt], 0, 0, 0);
            }
        }
        __syncthreads();   // reads done; next stage may overwrite
    }

    const float scale = (z == 0) ? 0.125f : 1.0f;
    #pragma unroll
    for (int nt = 0; nt < 4; nt++) {
        const int cn = n0 + wc * 64 + nt * 16 + mrow;
        const float bs = bias[cn];
        const int h = cn >> 6, d = cn & 63;
        #pragma unroll
        for (int mt = 0; mt < 4; mt++) {
            #pragma unroll
            for (int reg = 0; reg < 4; reg++) {
                const int rm = m0 + wr * 64 + mt * 16 + quad * 4 + reg;
                const int b = rm >> 11, s = rm & (S_ - 1);
                const float v = acc[mt][nt][reg] + bs;
                if (z == 2) {
                    // transposed: Vt[bh][d][s]
                    Vt[((size_t)(b * H_ + h) * D_ + d) * S_ + s] = bf16rn(v);
                } else {
                    const size_t idx = ((size_t)(b * H_ + h) * S_ + s) * D_ + d;
                    const float vs = v * scale;
                    const unsigned short hb = bf16rn(vs);
                    const unsigned short lb = bf16rn(vs - bfhi2f(hb));
                    if (z == 0) { Qh[idx] = hb; Ql[idx] = lb; }
                    else        { Kh[idx] = hb; Kl[idx] = lb; }
                }
            }
        }
    }
}

// ---------------- O-GEMM: out = AO @ Wo + bo (fp32 out), 128x128 LDS-staged --------
__global__ __launch_bounds__(256) void gemm_o_k(
    const unsigned short* __restrict__ Ah, const unsigned short* __restrict__ Al,
    const unsigned short* __restrict__ Bth, const unsigned short* __restrict__ Btl,
    const float* __restrict__ bias, float* __restrict__ Y)
{
    const int tid = threadIdx.x;
    const int lane = tid & 63;
    const int w = tid >> 6;
    const int wr = w >> 1, wc = w & 1;
    const int m0 = blockIdx.y * 128;
    const int n0 = blockIdx.x * 128;
    const int mrow = lane & 15, quad = lane >> 4;

    __shared__ __align__(16) unsigned short lds[16384];
    unsigned short* ldsAh = lds;
    unsigned short* ldsAl = lds + 4096;
    unsigned short* ldsBh = lds + 8192;
    unsigned short* ldsBl = lds + 12288;

    f32x4 acc[4][4];
    #pragma unroll
    for (int mt = 0; mt < 4; mt++)
        #pragma unroll
        for (int nt = 0; nt < 4; nt++)
            acc[mt][nt] = (f32x4){0.f, 0.f, 0.f, 0.f};

    const int srow = w * 32 + (lane >> 2);
    const int scol = (lane & 3) * 8;
    const size_t aoff = (size_t)(m0 + srow) * HID_ + scol;
    const size_t boff = (size_t)(n0 + srow) * HID_ + scol;
    unsigned short* dst0 = lds + (w * 32) * 32;
    unsigned short* dst1 = lds + (w * 32 + 16) * 32;

    #pragma unroll 1
    for (int k0 = 0; k0 < HID_; k0 += 32) {
        gld_lds16(Ah  + aoff + k0,             dst0);
        gld_lds16(Ah  + aoff + k0 + 16 * HID_, dst1);
        gld_lds16(Al  + aoff + k0,             dst0 + 4096);
        gld_lds16(Al  + aoff + k0 + 16 * HID_, dst1 + 4096);
        gld_lds16(Bth + boff + k0,             dst0 + 8192);
        gld_lds16(Bth + boff + k0 + 16 * HID_, dst1 + 8192);
        gld_lds16(Btl + boff + k0,             dst0 + 12288);
        gld_lds16(Btl + boff + k0 + 16 * HID_, dst1 + 12288);
        __syncthreads();

        short8 bh[4], bl[4];
        #pragma unroll
        for (int nt = 0; nt < 4; nt++) {
            const int br = (wc * 64 + nt * 16 + mrow) * 32 + quad * 8;
            bh[nt] = *(const short8*)&ldsBh[br];
            bl[nt] = *(const short8*)&ldsBl[br];
        }
        #pragma unroll
        for (int mt = 0; mt < 4; mt++) {
            const int ar = (wr * 64 + mt * 16 + mrow) * 32 + quad * 8;
            const short8 ah = *(const short8*)&ldsAh[ar];
            const short8 al = *(const short8*)&ldsAl[ar];
            #pragma unroll
            for (int nt = 0; nt < 4; nt++) {
                acc[mt][nt] = __builtin_amdgcn_mfma_f32_16x16x32_bf16(al, bh[nt], acc[mt][nt], 0, 0, 0);
                acc[mt][nt] = __builtin_amdgcn_mfma_f32_16x16x32_bf16(ah, bl[nt], acc[mt][nt], 0, 0, 0);
                acc[mt][nt] = __builtin_amdgcn_mfma_f32_16x16x32_bf16(ah, bh[nt], acc[mt][nt], 0, 0, 0);
            }
        }
        __syncthreads();
    }

    #pragma unroll
    for (int nt = 0; nt < 4; nt++) {
        const int cn = n0 + wc * 64 + nt * 16 + mrow;
        const float bs = bias[cn];
        #pragma unroll
        for (int mt = 0; mt < 4; mt++)
            #pragma unroll
            for (int reg = 0; reg < 4; reg++) {
                const int rm = m0 + wr * 64 + mt * 16 + quad * 4 + reg;
                Y[(size_t)rm * HID_ + cn] = acc[mt][nt][reg] + bs;
            }
    }
}

// ---------------- fused MFMA scores + exact top-204 + DENSE-MFMA sparse-softmax PV ----
// ROUND-11 (resubmitted after infra failure): r9 layout restored (r10's pads/dbuf
// were net-negative: conflicts halved but dur +2%). Work reduction instead (the
// only lever that has moved attn):
//  (a) score phase drops the Al*Bl MFMA (4 -> 3 terms, like the GEMMs since r2):
//      64 -> 48 score MFMAs/wave. Added error ~2^-16 relative — same order as the
//      split-bf16 input representation error already present.
//  (b) sc stores f2u_ord-mapped uints (mapping folded into the MFMA-shadowed write
//      side; extraction becomes a bare LDS read). Bit-identical uu.
__global__ __launch_bounds__(1024, 8) void attn_topk_k(
    const unsigned short* __restrict__ Qhi, const unsigned short* __restrict__ Qlo,
    const unsigned short* __restrict__ Khi, const unsigned short* __restrict__ Klo,
    const unsigned short* __restrict__ Vt,
    unsigned short* __restrict__ AOh, unsigned short* __restrict__ AOl)
{
    const int tid = threadIdx.x;
    const int wv = tid >> 6;                  // 0..15 — this wave's query row
    const int lane = tid & 63;
    // XCD-locality remap: 4 bh per XCD -> K+Vt working set < one L2
    const int xcd = blockIdx.x & 7;
    const int w = blockIdx.x >> 3;
    const int bh = xcd * 4 + (w >> 7);
    const int q0 = (w & 127) * QT_;
    const int b = bh >> 4, h = bh & (H_ - 1);

    __shared__ __align__(16) unsigned char smem[65536 + 4096 + 64 + 2 * 16 * QRS_ * 2];
    unsigned (*sc)[512] = (unsigned (*)[512])smem;    // ordered-uint scores [16][512]
    unsigned short* w16 = (unsigned short*)smem;      // weights view [64][16][32] (64 KB)
    float* partial = (float*)(smem + 65536);          // [16][64]
    float* denomL  = (float*)(smem + 65536 + 4096);   // [16]
    unsigned short* qh_l = (unsigned short*)(smem + 65536 + 4096 + 64);  // [16][QRS_]
    unsigned short* ql_l = qh_l + 16 * QRS_;

    const int mrow = lane & 15, quad = lane >> 4;

    // ---- stage Q (16 rows x 64 d, hi+lo) into LDS: 1 ushort/plane/thread ----
    {
        const int row = tid >> 6, d = tid & 63;
        const size_t g = ((size_t)bh * S_ + q0 + row) * D_ + d;
        qh_l[row * QRS_ + d] = Qhi[g];
        ql_l[row * QRS_ + d] = Qlo[g];
    }
    __syncthreads();

    const unsigned short* Kh_b = Khi + (size_t)bh * S_ * D_;   // SGPR base
    const unsigned short* Kl_b = Klo + (size_t)bh * S_ * D_;
    unsigned uu[32];   // slot (r*8+c) <-> key j = r*512 + c*64 + lane

    const int qoff = mrow * QRS_;

    #pragma unroll
    for (int r = 0; r < 4; r++) {
        int koff = (r * 512 + wv * 32 + mrow) * D_ + quad * 8;   // 32-bit voffset
        #pragma unroll 1
        for (int tl = 0; tl < 2; tl++) {
            f32x4 acc = {0.f, 0.f, 0.f, 0.f};
            {   // k = 0..31: Q half 0 from LDS, B half 0 from global (3-term)
                const short8 Ah0 = *(const short8*)&qh_l[qoff + quad * 8];
                const short8 Al0 = *(const short8*)&ql_l[qoff + quad * 8];
                const short8 Bh0 = *(const short8*)&Kh_b[koff];
                const short8 Bl0 = *(const short8*)&Kl_b[koff];
                __builtin_amdgcn_s_setprio(1);
                acc = __builtin_amdgcn_mfma_f32_16x16x32_bf16(Al0, Bh0, acc, 0, 0, 0);
                acc = __builtin_amdgcn_mfma_f32_16x16x32_bf16(Ah0, Bl0, acc, 0, 0, 0);
                acc = __builtin_amdgcn_mfma_f32_16x16x32_bf16(Ah0, Bh0, acc, 0, 0, 0);
                __builtin_amdgcn_s_setprio(0);
            }
            {   // k = 32..63: Q half 1, B half 1 (same registers recycled, 3-term)
                const short8 Ah1 = *(const short8*)&qh_l[qoff + 32 + quad * 8];
                const short8 Al1 = *(const short8*)&ql_l[qoff + 32 + quad * 8];
                const short8 Bh1 = *(const short8*)&Kh_b[koff + 32];
                const short8 Bl1 = *(const short8*)&Kl_b[koff + 32];
                __builtin_amdgcn_s_setprio(1);
                acc = __builtin_amdgcn_mfma_f32_16x16x32_bf16(Al1, Bh1, acc, 0, 0, 0);
                acc = __builtin_amdgcn_mfma_f32_16x16x32_bf16(Ah1, Bl1, acc, 0, 0, 0);
                acc = __builtin_amdgcn_mfma_f32_16x16x32_bf16(Ah1, Bh1, acc, 0, 0, 0);
                __builtin_amdgcn_s_setprio(0);
            }
            // C: row = quad*4+reg (0..15 = query), col = lane&15 (key in tile);
            // f2u_ord folded into the write (MFMA-shadowed side)
            const int colb = wv * 32 + tl * 16 + mrow;
            #pragma unroll
            for (int reg = 0; reg < 4; reg++)
                sc[quad * 4 + reg][colb] = f2u_ord(acc[reg]);
            koff += 16 * D_;
        }
        __syncthreads();   // round-r strips written
        #pragma unroll
        for (int c = 0; c < 8; c++)
            uu[r * 8 + c] = sc[wv][c * 64 + lane];
        __syncthreads();   // reads done; next round (or weights) may overwrite
    }

    // row max (ordered uints); sparse row includes zeros -> clamp to 0
    unsigned um = 0u;
    #pragma unroll
    for (int c = 0; c < 32; c++) { const unsigned t = uu[c]; um = (t > um) ? t : um; }
    um = wave_max_u(um);
    um = __builtin_amdgcn_readfirstlane(um);   // keep threshold chain scalar
    const float m = fmaxf(u2f_ord(um), 0.0f);
    const float em = __expf(-m);

    // ---- exact threshold: ballot-counted radix-2 bit-descent ----
    unsigned p = 0;
    int cge = S_;          // count of values >= p (p=0 -> all)
    #pragma unroll 1
    for (int bit = 31; bit >= 0; bit--) {
        if (cge == KEEP_) break;
        const unsigned trial = p | (1u << bit);
        if (trial > um) continue;
        int c = 0;
        #pragma unroll
        for (int i = 0; i < 32; i++)
            c += (int)__popcll(__ballot(uu[i] >= trial));
        if (c >= KEEP_) { p = trial; cge = c; }
    }
    const unsigned T = p;

    // ---- tie selection ----
    unsigned tieMask = 0;
    if (cge == KEEP_) {
        // exact hit: all ties at T are selected
        #pragma unroll
        for (int c = 0; c < 32; c++)
            if (uu[c] == T) tieMask |= 1u << c;
    } else {
        // rare path: take first `rem' ties in ascending j
        int cgt = 0;
        #pragma unroll
        for (int i = 0; i < 32; i++)
            cgt += (int)__popcll(__ballot(uu[i] > T));
        int need = KEEP_ - cgt;                // #ties to take (>=1)
        const unsigned long long below = (1ULL << lane) - 1ULL;
        #pragma unroll
        for (int c = 0; c < 32; c++) {
            const bool eq = (uu[c] == T);
            const unsigned long long mg = __ballot(eq);
            if (eq && (int)__popcll(mg & below) < need) tieMask |= 1u << c;
            const int cnt = (int)__popcll(mg);
            need -= (cnt < need) ? cnt : need;
        }
    }

    // ---- dense bf16 weight row + denominator from stored weights ----
    // slot i = r*8+c2 -> key j = r*512 + c2*64 + lane -> tile ch = j>>5 =
    // r*16 + c2*2 + (lane>>5), kk = lane&31; layout w16[ch*512 + q*32 + kk]
    float esum = 0.f;
    {
        const int lh = lane >> 5;
        const int kk = lane & 31;
        #pragma unroll
        for (int i = 0; i < 32; i++) {
            const unsigned u = uu[i];
            const bool sel = (u > T) || ((tieMask >> i) & 1u);
            const float wgt = sel ? __expf(u2f_ord(u) - m) : em;
            const unsigned short wb = bf16rn(wgt);
            esum += bfhi2f(wb);
            const int ch = (i >> 3) * 16 + (i & 7) * 2 + lh;
            w16[ch * 512 + wv * 32 + kk] = wb;
        }
    }
    const float denom = wave_sum(esum);
    if (lane == 0) denomL[wv] = denom;
    partial[tid] = 0.f;    // zero PV accumulator (exactly 1024 floats)
    __syncthreads();       // weights + denoms + zeroed partial visible

    // ---- PV via MFMA: wave = (ntile = wv&3 -> d-cols, kq = wv>>2 -> key quarter)
    {
        const int ntile = wv & 3;
        const int kq = wv >> 2;
        const unsigned short* VtB =
            Vt + ((size_t)bh * D_ + ntile * 16 + mrow) * S_ + kq * 512 + quad * 8;
        const unsigned short* wbase = w16 + kq * 16 * 512 + mrow * 32 + quad * 8;
        f32x4 pacc0 = {0.f, 0.f, 0.f, 0.f};
        f32x4 pacc1 = {0.f, 0.f, 0.f, 0.f};
        #pragma unroll 2
        for (int ch = 0; ch < 16; ch += 2) {
            const short8 aw0 = *(const short8*)&wbase[ch * 512];
            const short8 bv0 = *(const short8*)&VtB[ch * 32];
            const short8 aw1 = *(const short8*)&wbase[(ch + 1) * 512];
            const short8 bv1 = *(const short8*)&VtB[(ch + 1) * 32];
            pacc0 = __builtin_amdgcn_mfma_f32_16x16x32_bf16(aw0, bv0, pacc0, 0, 0, 0);
            pacc1 = __builtin_amdgcn_mfma_f32_16x16x32_bf16(aw1, bv1, pacc1, 0, 0, 0);
        }
        const f32x4 pacc = pacc0 + pacc1;
        // C: row = quad*4+reg (query), col = lane&15 (d within ntile)
        #pragma unroll
        for (int reg = 0; reg < 4; reg++)
            atomicAdd(&partial[(quad * 4 + reg) * 64 + ntile * 16 + mrow], pacc[reg]);
    }
    __syncthreads();   // partials reduced

    // ---- normalize, write AO (bf16 hi/lo) ----
    {
        const int q = tid >> 6;       // 0..15
        const int d = tid & 63;
        const float o = partial[q * 64 + d] / denomL[q];
        const unsigned short hb = bf16rn(o);
        const unsigned short lb = bf16rn(o - bfhi2f(hb));
        const size_t oidx = ((size_t)(b * S_ + q0 + q)) * HID_ + h * D_ + d;
        AOh[oidx] = hb;
        AOl[oidx] = lb;
    }
}

extern "C" void kernel_launch(void* const* d_in, const int* in_sizes, int n_in,
                              void* d_out, int out_size, void* d_ws, size_t ws_size,
                              hipStream_t stream) {
    const float* x  = (const float*)d_in[0];
    const float* Wq = (const float*)d_in[1];
    const float* bq = (const float*)d_in[2];
    const float* Wk = (const float*)d_in[3];
    const float* bk = (const float*)d_in[4];
    const float* Wv = (const float*)d_in[5];
    const float* bv = (const float*)d_in[6];
    const float* Wo = (const float*)d_in[7];
    const float* bo = (const float*)d_in[8];
    float* out = (float*)d_out;

    const size_t NQ = (size_t)B_ * H_ * S_ * D_;   // 4,194,304 elements
    const size_t NW = (size_t)HID_ * HID_;         // 1,048,576 elements
    unsigned short* p = (unsigned short*)d_ws;
    unsigned short* xh   = p; p += NQ;   // also AOh (x dead after QKV GEMM)
    unsigned short* xl   = p; p += NQ;   // also AOl
    unsigned short* Wt_h[4];
    unsigned short* Wt_l[4];
    for (int i = 0; i < 4; i++) { Wt_h[i] = p; p += NW; Wt_l[i] = p; p += NW; }
    unsigned short* Qhi = p; p += NQ;
    unsigned short* Qlo = p; p += NQ;
    unsigned short* Khi = p; p += NQ;
    unsigned short* Klo = p; p += NQ;
    unsigned short* Vt  = p; p += NQ;
    unsigned short* AOh = xh;
    unsigned short* AOl = xl;

    dim3 blk(256);
    conv_x_k<<<dim3(NQ / 1024), blk, 0, stream>>>(x, xh, xl);
    conv_wT_k<<<dim3(16, 16), blk, 0, stream>>>(Wq, Wt_h[0], Wt_l[0]);
    conv_wT_k<<<dim3(16, 16), blk, 0, stream>>>(Wk, Wt_h[1], Wt_l[1]);
    conv_wT_k<<<dim3(16, 16), blk, 0, stream>>>(Wv, Wt_h[2], Wt_l[2]);
    conv_wT_k<<<dim3(16, 16), blk, 0, stream>>>(Wo, Wt_h[3], Wt_l[3]);

    dim3 gqkv(HID_ / 128, (B_ * S_) / 128, 3);
    gemm_qkv_k<<<gqkv, blk, 0, stream>>>(xh, xl,
        Wt_h[0], Wt_l[0], Wt_h[1], Wt_l[1], Wt_h[2], Wt_l[2],
        bq, bk, bv, Qhi, Qlo, Khi, Klo, Vt);
    attn_topk_k<<<dim3(B_ * H_ * (S_ / QT_)), dim3(1024), 0, stream>>>(
        Qhi, Qlo, Khi, Klo, Vt, AOh, AOl);
    dim3 go(HID_ / 128, (B_ * S_) / 128);
    gemm_o_k<<<go, blk, 0, stream>>>(AOh, AOl, Wt_h[3], Wt_l[3], bo, out);
}